// Round 4
// baseline (4839.815 us; speedup 1.0000x reference)
//
#include <hip/hip_runtime.h>

typedef unsigned short u16;
typedef unsigned int   u32;
typedef __attribute__((ext_vector_type(8))) short s8v;            // MFMA bf16 frag
typedef __attribute__((ext_vector_type(8))) unsigned short u8v;
typedef __attribute__((ext_vector_type(16))) float f32x16;

__device__ __forceinline__ float bf2f(u16 v) {
    union { u32 u; float f; } x; x.u = ((u32)v) << 16; return x.f;
}
__device__ __forceinline__ u16 f2bf(float f) {
    union { float f; u32 u; } x; x.f = f;
    return (u16)((x.u + 0x7fffu + ((x.u >> 16) & 1u)) >> 16);
}
__device__ __forceinline__ float sigf(float x)  { return 1.0f / (1.0f + __expf(-x)); }
__device__ __forceinline__ float tanhf_(float x){ return 1.0f - 2.0f / (__expf(2.0f * x) + 1.0f); }

constexpr int Bb = 256, Tt = 32, Ss = 2048, Aa = 64, Pp = 128, SAPd = 2240;

typedef const __attribute__((address_space(1))) unsigned int* gp1_t;
typedef __attribute__((address_space(3))) unsigned int* lp3_t;
__device__ __forceinline__ void gl16(const void* g, void* l) {
    __builtin_amdgcn_global_load_lds((gp1_t)g, (lp3_t)l, 16, 0, 0);
}
template<int N> __device__ __forceinline__ void vmw() {
    if constexpr (N == 6)      asm volatile("s_waitcnt vmcnt(6)" ::: "memory");
    else if constexpr (N == 3) asm volatile("s_waitcnt vmcnt(3)" ::: "memory");
    else                       asm volatile("s_waitcnt vmcnt(0)" ::: "memory");
}

// 1 = bf16 inputs; detector kept as insurance.
__global__ void detect_k(const u32* __restrict__ st, int* __restrict__ flag) {
    u32 w = st[threadIdx.x];
    int e = (w >> 7) & 0xFF;
    unsigned long long m = __ballot(e >= 100 && e <= 140);
    if (threadIdx.x == 0) flag[0] = (__popcll(m) >= 32) ? 1 : 0;
}

// hs0 build + rewards zero + (big ws) fc1s = fc1_W[:,:S] + fc1_W[:,S:]
__global__ __launch_bounds__(256)
void prep_k(const void* __restrict__ state, const void* __restrict__ act,
            const void* __restrict__ latent, const void* __restrict__ fc1W,
            u16* __restrict__ hs, u16* __restrict__ fc1s, float* __restrict__ rewbuf,
            const int* __restrict__ flagp, int big)
{
    const bool bfe = (flagp[0] == 1);
    int g0 = blockIdx.x * 256 + threadIdx.x;
    int stride = gridDim.x * 256;
    for (int i = g0; i < Bb * SAPd; i += stride) {
        int b = i / SAPd, k = i - b * SAPd;
        const void* p; size_t src;
        if (k < Ss)           { p = state;  src = (size_t)b * Ss + k; }
        else if (k < Ss + Aa) { p = act;    src = (size_t)b * (Tt * Aa) + (k - Ss); }
        else                  { p = latent; src = (size_t)b * Pp + (k - Ss - Aa); }
        hs[i] = bfe ? ((const u16*)p)[src] : f2bf(((const float*)p)[src]);
    }
    for (int i = g0; i < Tt * Bb; i += stride) rewbuf[i] = 0.0f;
    if (big) {
        for (int i = g0; i < Ss * Ss; i += stride) {
            int n = i >> 11, k = i & 2047;
            float s;
            if (bfe) s = bf2f(((const u16*)fc1W)[(size_t)n * 4096 + k])
                       + bf2f(((const u16*)fc1W)[(size_t)n * 4096 + 2048 + k]);
            else     s = ((const float*)fc1W)[(size_t)n * 4096 + k]
                       + ((const float*)fc1W)[(size_t)n * 4096 + 2048 + k];
            fc1s[i] = f2bf(s);
        }
    }
}

// C[256 x 2048] = relu(A @ W^T (+bias)).  Tile 32(M) x 64(N), 4 waves.
// 32x32x16 MFMA; waves: (w&1)=col-tile (32 cols), (w>>1)=K-half of the K-step.
// K-step = KSTEP (64 or 128).  3 LDS buffers, depth-2 prefetch, counted vmcnt.
//
// STAGING (the R3 bug fix): global_load_lds writes at wave-uniform base +
// lane*16 — NOT per-lane scatter.  So staging is organized in 1KB LDS
// segments: one gl16 per wave per segment, LDS dst = segment base (uniform),
// and lane X supplies the global data belonging at seg*1024 + X*16:
//   row = s*(64/CH) + lane/CH, chunk c = lane&(CH-1), global chunk
//   cg = c ^ (row&(CH-1))  (XOR swizzle applied on the per-lane GLOBAL addr).
// ds_read applies the same XOR -> <=2-way bank aliasing (free).
// Epilogue: K-half waves reduce via 8KB LDS overlay, waves 0/1 store.
template<int K, int KSTEP, bool BIAS, bool WC, bool FOLD, bool ACT, bool WBF>
__global__ __launch_bounds__(256)
void gemm_k(const u16* __restrict__ Ap, const void* __restrict__ Wp,
            const void* __restrict__ biasp, u16* __restrict__ outp,
            float* __restrict__ cellp,
            u16* __restrict__ hsp, const void* __restrict__ actp, int t,
            const int* __restrict__ flagp)
{
    constexpr int CH   = KSTEP / 8;          // 16B chunks per row
    constexpr int RB   = CH * 16;            // row bytes
    constexpr int RPS  = 64 / CH;            // rows per 1KB segment
    constexpr int ABYT = 32 * RB, BBYT = 64 * RB, BUF = ABYT + BBYT;
    constexpr int NK   = K / KSTEP;
    constexpr int GLN  = 3 * CH / 8;         // gl16 per thread per STAGE
    constexpr int KS2  = KSTEP / 32;         // 16-k subtiles per K-half per wave
    __shared__ __align__(16) char smem[3 * BUF];
    const bool bfe = (flagp[0] == 1);
    const int tid = threadIdx.x;
    const int lane = tid & 63, w = tid >> 6, ct = w & 1, kh = w >> 1;
    const int arr = lane & 31, hi = lane >> 5;
    const int r0 = blockIdx.y * 32, c0 = blockIdx.x * 64;

    if (ACT) {          // refresh act_t slice of hs before the fc GEMM reads it
        if (blockIdx.y == 0) {
            int i = blockIdx.x * 512 + tid * 2;         // 32 blocks x 512 = 16384
            int b = i >> 6, a2 = i & 63;
            if (bfe) {
                u32 v = *(const u32*)((const u16*)actp + ((size_t)b * Tt + t) * Aa + a2);
                *(u32*)(hsp + (size_t)b * SAPd + Ss + a2) = v;
            } else {
                const float* s = (const float*)actp + ((size_t)b * Tt + t) * Aa + a2;
                *(u32*)(hsp + (size_t)b * SAPd + Ss + a2) =
                    (u32)f2bf(s[0]) | ((u32)f2bf(s[1]) << 16);
            }
            vmw<0>();                                   // retire before counted pipeline
        }
    }

    // per-lane staging coordinates (same for every segment)
    const int srow_in_seg = lane / CH;       // row offset within a segment
    const int sc  = lane & (CH - 1);         // LDS chunk this lane fills

    f32x16 acc = {};
    const int brr = ct * 32 + arr;
    const int sa = arr & (CH - 1), sb = brr & (CH - 1);

    auto COMPUTE = [&](int p) {
        const char* bufA = smem + p * BUF;
        const char* bufB = bufA + ABYT;
        #pragma unroll
        for (int x = 0; x < KS2; x++) {
            int kk = kh * KS2 + x;
            s8v a = *(const s8v*)(bufA + arr * RB + ((((kk << 1) | hi) ^ sa) << 4));
            s8v b = *(const s8v*)(bufB + brr * RB + ((((kk << 1) | hi) ^ sb) << 4));
            acc = __builtin_amdgcn_mfma_f32_32x32x16_bf16(a, b, acc, 0, 0, 0);
        }
    };

    const bool fast = (WBF || bfe) && !FOLD;
    if (fast) {
        const u16* W16 = (const u16*)Wp;
        auto STAGE = [&](int kt, int p) {
            char* bufA = smem + p * BUF;
            char* bufB = bufA + ABYT;
            int kb = kt * KSTEP;
            #pragma unroll
            for (int i = 0; i < CH / 8; i++) {           // A: CH/2 segs, CH/8 per wave
                int s = w * (CH / 8) + i;
                int row = s * RPS + srow_in_seg;
                int cg = sc ^ (row & (CH - 1));
                gl16(Ap + (size_t)(r0 + row) * K + kb + cg * 8, bufA + s * 1024);
            }
            #pragma unroll
            for (int i = 0; i < CH / 4; i++) {           // B: CH segs, CH/4 per wave
                int s = w * (CH / 4) + i;
                int row = s * RPS + srow_in_seg;
                int cg = sc ^ (row & (CH - 1));
                gl16(W16 + (size_t)(c0 + row) * K + kb + cg * 8, bufB + s * 1024);
            }
        };
        STAGE(0, 0); STAGE(1, 1);
        for (int k = 0; k < NK - 2; k++) {
            vmw<GLN>();                                 // tile k landed (k+1 in flight)
            __builtin_amdgcn_s_barrier();
            STAGE(k + 2, (k + 2) % 3);
            COMPUTE(k % 3);
        }
        vmw<GLN>();
        __builtin_amdgcn_s_barrier();
        COMPUTE((NK - 2) % 3);
        vmw<0>();
        __builtin_amdgcn_s_barrier();
        COMPUTE((NK - 1) % 3);
    } else {
        // fallback: A via gl16 (activations always bf16), B reg-staged (f32 / FOLD)
        const int br  = tid >> 2;                // B row 0..63
        const int bc0 = (tid & 3) * (CH / 4);    // B chunk slots per thread: CH/4
        const int wrow = c0 + br;
        u8v  rbh[2 * (CH / 4)];
        float4 rff[4 * (CH / 4)];
        auto ISSUE = [&](int kt) {
            int kb = kt * KSTEP;
            #pragma unroll
            for (int i = 0; i < CH / 4; i++) {
                int c = bc0 + i, cg = c ^ (br & (CH - 1));
                if (FOLD) {
                    if (bfe) {
                        const u16* p1 = (const u16*)Wp + (size_t)wrow * (2 * K) + kb + cg * 8;
                        rbh[2 * i] = *(const u8v*)p1; rbh[2 * i + 1] = *(const u8v*)(p1 + K);
                    } else {
                        const float* p1 = (const float*)Wp + (size_t)wrow * (2 * K) + kb + cg * 8;
                        rff[4 * i]     = *(const float4*)p1;
                        rff[4 * i + 1] = *(const float4*)(p1 + 4);
                        rff[4 * i + 2] = *(const float4*)(p1 + K);
                        rff[4 * i + 3] = *(const float4*)(p1 + K + 4);
                    }
                } else {
                    const float* p1 = (const float*)Wp + (size_t)wrow * K + kb + cg * 8;
                    rff[4 * i]     = *(const float4*)p1;
                    rff[4 * i + 1] = *(const float4*)(p1 + 4);
                }
            }
        };
        auto STAGE_A = [&](int kt, int p) {
            char* bufA = smem + p * BUF;
            int kb = kt * KSTEP;
            #pragma unroll
            for (int i = 0; i < CH / 8; i++) {
                int s = w * (CH / 8) + i;
                int row = s * RPS + srow_in_seg;
                int cg = sc ^ (row & (CH - 1));
                gl16(Ap + (size_t)(r0 + row) * K + kb + cg * 8, bufA + s * 1024);
            }
        };
        auto COMMIT = [&](int p) {
            char* bufB = smem + p * BUF + ABYT;
            #pragma unroll
            for (int i = 0; i < CH / 4; i++) {
                u8v v;
                if (FOLD) {
                    if (bfe) {
                        #pragma unroll
                        for (int j = 0; j < 8; j++)
                            v[j] = f2bf(bf2f(rbh[2 * i][j]) + bf2f(rbh[2 * i + 1][j]));
                    } else {
                        float a0[8], a1[8];
                        *(float4*)&a0[0] = rff[4 * i];     *(float4*)&a0[4] = rff[4 * i + 1];
                        *(float4*)&a1[0] = rff[4 * i + 2]; *(float4*)&a1[4] = rff[4 * i + 3];
                        #pragma unroll
                        for (int j = 0; j < 8; j++) v[j] = f2bf(a0[j] + a1[j]);
                    }
                } else {
                    float a0[8];
                    *(float4*)&a0[0] = rff[4 * i]; *(float4*)&a0[4] = rff[4 * i + 1];
                    #pragma unroll
                    for (int j = 0; j < 8; j++) v[j] = f2bf(a0[j]);
                }
                *(u8v*)(bufB + br * RB + (bc0 + i) * 16) = v;   // plain per-lane ds_write: OK
            }
        };
        ISSUE(0); STAGE_A(0, 0);
        for (int k = 0; k < NK; k++) {
            __syncthreads();                 // drains vmcnt: A(k) in LDS, B(k) in regs
            COMMIT(k & 1);
            __syncthreads();
            if (k + 1 < NK) { STAGE_A(k + 1, (k + 1) & 1); ISSUE(k + 1); }
            COMPUTE(k & 1);
        }
    }

    // K-half reduction + store
    __syncthreads();
    float* red = (float*)smem;
    if (w >= 2) {
        #pragma unroll
        for (int r = 0; r < 16; r++) red[ct * 1024 + r * 64 + lane] = acc[r];
    }
    __syncthreads();
    if (w < 2) {
        #pragma unroll
        for (int r = 0; r < 16; r++) acc[r] += red[ct * 1024 + r * 64 + lane];
        const int col = c0 + ct * 32 + arr;
        float bv = 0.0f;
        if (BIAS) bv = bfe ? bf2f(((const u16*)biasp)[col]) : ((const float*)biasp)[col];
        #pragma unroll
        for (int r = 0; r < 16; r++) {
            int row = r0 + (r & 3) + 8 * (r >> 2) + 4 * hi;
            float v = fmaxf(acc[r] + bv, 0.0f);
            outp[(size_t)row * 2048 + col] = f2bf(v);
            if (WC) cellp[(size_t)row * 2048 + col] = v;
        }
    }
}

// Fused: cc = relu(x2 @ W_W^T) + LSTM gates + cell + h' (hs & preds) + reward partial.
// Same 32x32x16 pipeline, KSTEP=128; B-tile row b <-> W_W row (b>>4)*2048+j0+(b&15).
__global__ __launch_bounds__(256)
void wgates_k(const u16* __restrict__ Ap, const void* __restrict__ Wp,
              float* __restrict__ cbuf, u16* __restrict__ hsp,
              void* __restrict__ dout, const void* __restrict__ rwWp,
              float* __restrict__ rewbuf, int t, const int* __restrict__ flagp)
{
    constexpr int K = 2048, KSTEP = 128, CH = 16, RB = 256, RPS = 4;
    constexpr int ABYT = 32 * RB, BBYT = 64 * RB, BUF = ABYT + BBYT;
    constexpr int NK = K / KSTEP, KS2 = KSTEP / 32;
    __shared__ __align__(16) char smem[3 * BUF];
    const bool bfe = (flagp[0] == 1);
    const int tid = threadIdx.x;
    const int lane = tid & 63, w = tid >> 6, ct = w & 1, kh = w >> 1;
    const int arr = lane & 31, hi = lane >> 5;
    const int r0 = blockIdx.y * 32, j0 = blockIdx.x * 16;

    const int srow_in_seg = lane / CH;
    const int sc  = lane & (CH - 1);

    f32x16 acc = {};
    const int brr = ct * 32 + arr;
    const int sa = arr & (CH - 1), sb = brr & (CH - 1);

    auto COMPUTE = [&](int p) {
        const char* bufA = smem + p * BUF;
        const char* bufB = bufA + ABYT;
        #pragma unroll
        for (int x = 0; x < KS2; x++) {
            int kk = kh * KS2 + x;
            s8v a = *(const s8v*)(bufA + arr * RB + ((((kk << 1) | hi) ^ sa) << 4));
            s8v b = *(const s8v*)(bufB + brr * RB + ((((kk << 1) | hi) ^ sb) << 4));
            acc = __builtin_amdgcn_mfma_f32_32x32x16_bf16(a, b, acc, 0, 0, 0);
        }
    };

    if (bfe) {
        const u16* W16 = (const u16*)Wp;
        auto STAGE = [&](int kt, int p) {
            char* bufA = smem + p * BUF;
            char* bufB = bufA + ABYT;
            int kb = kt * KSTEP;
            #pragma unroll
            for (int i = 0; i < CH / 8; i++) {           // A: 8 segs, 2 per wave
                int s = w * (CH / 8) + i;
                int row = s * RPS + srow_in_seg;
                int cg = sc ^ (row & (CH - 1));
                gl16(Ap + (size_t)(r0 + row) * K + kb + cg * 8, bufA + s * 1024);
            }
            #pragma unroll
            for (int i = 0; i < CH / 4; i++) {           // B: 16 segs, 4 per wave
                int s = w * (CH / 4) + i;
                int row = s * RPS + srow_in_seg;
                int wr = (row >> 4) * 2048 + j0 + (row & 15);
                int cg = sc ^ (row & (CH - 1));
                gl16(W16 + (size_t)wr * K + kb + cg * 8, bufB + s * 1024);
            }
        };
        STAGE(0, 0); STAGE(1, 1);
        for (int k = 0; k < NK - 2; k++) {
            vmw<6>();
            __builtin_amdgcn_s_barrier();
            STAGE(k + 2, (k + 2) % 3);
            COMPUTE(k % 3);
        }
        vmw<6>();
        __builtin_amdgcn_s_barrier();
        COMPUTE((NK - 2) % 3);
        vmw<0>();
        __builtin_amdgcn_s_barrier();
        COMPUTE((NK - 1) % 3);
    } else {
        const int br  = tid >> 2;
        const int bc0 = (tid & 3) * (CH / 4);
        const int wrow = (br >> 4) * 2048 + j0 + (br & 15);
        float4 rff[2 * (CH / 4)];
        auto ISSUE = [&](int kt) {
            int kb = kt * KSTEP;
            #pragma unroll
            for (int i = 0; i < CH / 4; i++) {
                int c = bc0 + i, cg = c ^ (br & (CH - 1));
                const float* p1 = (const float*)Wp + (size_t)wrow * K + kb + cg * 8;
                rff[2 * i]     = *(const float4*)p1;
                rff[2 * i + 1] = *(const float4*)(p1 + 4);
            }
        };
        auto STAGE_A = [&](int kt, int p) {
            char* bufA = smem + p * BUF;
            int kb = kt * KSTEP;
            #pragma unroll
            for (int i = 0; i < CH / 8; i++) {
                int s = w * (CH / 8) + i;
                int row = s * RPS + srow_in_seg;
                int cg = sc ^ (row & (CH - 1));
                gl16(Ap + (size_t)(r0 + row) * K + kb + cg * 8, bufA + s * 1024);
            }
        };
        auto COMMIT = [&](int p) {
            char* bufB = smem + p * BUF + ABYT;
            #pragma unroll
            for (int i = 0; i < CH / 4; i++) {
                float a0[8];
                *(float4*)&a0[0] = rff[2 * i]; *(float4*)&a0[4] = rff[2 * i + 1];
                u8v v;
                #pragma unroll
                for (int j = 0; j < 8; j++) v[j] = f2bf(a0[j]);
                *(u8v*)(bufB + br * RB + (bc0 + i) * 16) = v;
            }
        };
        ISSUE(0); STAGE_A(0, 0);
        for (int k = 0; k < NK; k++) {
            __syncthreads();
            COMMIT(k & 1);
            __syncthreads();
            if (k + 1 < NK) { STAGE_A(k + 1, (k + 1) & 1); ISSUE(k + 1); }
            COMPUTE(k & 1);
        }
    }

    // K-half reduction -> relu(cc) into gate buffer
    __syncthreads();
    float* red  = (float*)smem;
    float* gbuf = (float*)(smem + 8192);     // [32 rows][16 j][4 gates] fp32 (8KB)
    if (w >= 2) {
        #pragma unroll
        for (int r = 0; r < 16; r++) red[ct * 1024 + r * 64 + lane] = acc[r];
    }
    __syncthreads();
    if (w < 2) {
        const int j = arr & 15, gate = ct * 2 + (arr >> 4);
        #pragma unroll
        for (int r = 0; r < 16; r++) {
            float v = acc[r] + red[ct * 1024 + r * 64 + lane];
            int row = (r & 3) + 8 * (r >> 2) + 4 * hi;
            gbuf[(row * 16 + j) * 4 + gate] = fmaxf(v, 0.0f);
        }
    }
    __syncthreads();

    const int row = tid >> 3, jj = (tid & 7) * 2;
    const int grow = r0 + row, jcol = j0 + jj;
    float2 cold = *(const float2*)&cbuf[(size_t)grow * 2048 + jcol];
    float rw0 = bfe ? bf2f(((const u16*)rwWp)[jcol])     : ((const float*)rwWp)[jcol];
    float rw1 = bfe ? bf2f(((const u16*)rwWp)[jcol + 1]) : ((const float*)rwWp)[jcol + 1];

    float cn[2], hnf[2];
    float coldv[2] = { cold.x, cold.y };
    float rsum = 0.0f;
    #pragma unroll
    for (int u = 0; u < 2; u++) {
        const float* gq = &gbuf[((row * 16) + jj + u) * 4];
        float ig = sigf(gq[0]), fg = sigf(gq[1]), og = sigf(gq[2]), tg = tanhf_(gq[3]);
        float c_ = fg * coldv[u] + ig * tg;
        float hn = og * tanhf_(c_);
        cn[u] = c_; hnf[u] = hn;
        rsum += hn * (u ? rw1 : rw0);
    }
    *(float2*)&cbuf[(size_t)grow * 2048 + jcol] = *(float2*)cn;
    u32 hpack = (u32)f2bf(hnf[0]) | ((u32)f2bf(hnf[1]) << 16);
    *(u32*)&hsp[(size_t)grow * SAPd + jcol] = hpack;
    size_t pb = ((size_t)t * 256 + grow) * 2048 + jcol;
    if (bfe) *(u32*)&((u16*)dout)[pb] = hpack;
    else     { ((float*)dout)[pb] = hnf[0]; ((float*)dout)[pb + 1] = hnf[1]; }

    rsum += __shfl_xor(rsum, 1);
    rsum += __shfl_xor(rsum, 2);
    rsum += __shfl_xor(rsum, 4);
    if ((tid & 7) == 0) atomicAdd(&rewbuf[t * 256 + grow], rsum);
}

__global__ void rewfin_k(const float* __restrict__ rewbuf, void* __restrict__ dout,
                         const void* __restrict__ rwb, const int* __restrict__ flagp) {
    const bool bfe = (flagp[0] == 1);
    int i = blockIdx.x * 256 + threadIdx.x;        // grid 32 -> 8192
    float rb = bfe ? bf2f(((const u16*)rwb)[0]) : ((const float*)rwb)[0];
    float v = rewbuf[i] + rb;
    size_t o = (size_t)Tt * Bb * Ss + i;           // 16777216
    if (bfe) ((u16*)dout)[o] = f2bf(v);
    else     ((float*)dout)[o] = v;
}

extern "C" void kernel_launch(void* const* d_in, const int* in_sizes, int n_in,
                              void* d_out, int out_size, void* d_ws, size_t ws_size,
                              hipStream_t stream)
{
    const void* state  = d_in[0];
    const void* act    = d_in[1];
    const void* latent = d_in[2];
    const void* fcW    = d_in[3];
    const void* fcb    = d_in[4];
    const void* fc1W   = d_in[5];
    const void* fc2W   = d_in[6];
    const void* WW     = d_in[7];
    const void* rwW    = d_in[8];
    const void* rwb    = d_in[9];
    char* ws = (char*)d_ws;

    // ws layout: small path 6.43 MB; big path (+fc1s) 14.81 MB (gated on ws_size)
    int*   flag   = (int*)  (ws + 0);
    u16*   hs     = (u16*)  (ws + 1024);
    u16*   h      = (u16*)  (ws + 1147904);
    u16*   x1     = (u16*)  (ws + 2196480);
    u16*   x2     = (u16*)  (ws + 3245056);
    float* cbuf   = (float*)(ws + 4293632);
    float* rewbuf = (float*)(ws + 6390784);
    u16*   fc1s   = (u16*)  (ws + 6423552);
    const bool big = ws_size >= 14812160ull;       // launch-invariant -> graph-safe

    detect_k<<<dim3(1), dim3(64), 0, stream>>>((const u32*)state, flag);
    prep_k<<<dim3(4096), dim3(256), 0, stream>>>(state, act, latent, fc1W,
                                                 hs, fc1s, rewbuf, flag, big ? 1 : 0);

    // hidden = cell = relu(fc(hs0))
    gemm_k<2240, 64, true, true, false, false, false><<<dim3(32, 8), dim3(256), 0, stream>>>(
        hs, fcW, fcb, h, cbuf, nullptr, nullptr, 0, flag);

    for (int t = 0; t < 32; t++) {
        // x1 = relu(h @ fc1sum^T); y==0 blocks also copy act_t into hs
        if (big)
            gemm_k<2048, 128, false, false, false, true, true><<<dim3(32, 8), dim3(256), 0, stream>>>(
                h, fc1s, nullptr, x1, nullptr, hs, act, t, flag);
        else
            gemm_k<2048, 128, false, false, true, true, false><<<dim3(32, 8), dim3(256), 0, stream>>>(
                h, fc1W, nullptr, x1, nullptr, hs, act, t, flag);
        // x2 = relu(x1 @ fc2^T)
        gemm_k<2048, 128, false, false, false, false, false><<<dim3(32, 8), dim3(256), 0, stream>>>(
            x1, fc2W, nullptr, x2, nullptr, nullptr, nullptr, 0, flag);
        // cc = relu(x2 @ W_W^T) fused with gates/cell/h'/preds/reward-partial
        wgates_k<<<dim3(128, 8), dim3(256), 0, stream>>>(
            x2, WW, cbuf, hs, d_out, rwW, rewbuf, t, flag);
        // h = relu(hs @ fc_W^T + b)   (carry discarded at t=31)
        if (t < 31)
            gemm_k<2240, 64, true, false, false, false, false><<<dim3(32, 8), dim3(256), 0, stream>>>(
                hs, fcW, fcb, h, nullptr, nullptr, nullptr, 0, flag);
    }
    rewfin_k<<<dim3(32), dim3(256), 0, stream>>>(rewbuf, d_out, rwb, flag);
}

// Round 5
// 3037.049 us; speedup vs baseline: 1.5936x; 1.5936x over previous
//
#include <hip/hip_runtime.h>

typedef unsigned short u16;
typedef unsigned int   u32;
typedef __attribute__((ext_vector_type(8))) short s8v;            // MFMA bf16 frag
typedef __attribute__((ext_vector_type(8))) unsigned short u8v;
typedef __attribute__((ext_vector_type(4))) float f32x4;

__device__ __forceinline__ float bf2f(u16 v) {
    union { u32 u; float f; } x; x.u = ((u32)v) << 16; return x.f;
}
__device__ __forceinline__ u16 f2bf(float f) {
    union { float f; u32 u; } x; x.f = f;
    return (u16)((x.u + 0x7fffu + ((x.u >> 16) & 1u)) >> 16);
}
__device__ __forceinline__ float sigf(float x)  { return 1.0f / (1.0f + __expf(-x)); }
__device__ __forceinline__ float tanhf_(float x){ return 1.0f - 2.0f / (__expf(2.0f * x) + 1.0f); }

constexpr int Bb = 256, Tt = 32, Ss = 2048, Aa = 64, Pp = 128, SAPd = 2240;

typedef const __attribute__((address_space(1))) unsigned int* gp1_t;
typedef __attribute__((address_space(3))) unsigned int* lp3_t;
__device__ __forceinline__ void gl16(const void* g, void* l) {
    __builtin_amdgcn_global_load_lds((gp1_t)g, (lp3_t)l, 16, 0, 0);
}
#define VMW3() asm volatile("s_waitcnt vmcnt(3)" ::: "memory")
#define VMW0() asm volatile("s_waitcnt vmcnt(0)" ::: "memory")

// XCD-aware decode: hardware round-robins linear block id across the 8 XCDs,
// so xcd = id&7.  Give each XCD a contiguous slice of the N dimension (bx) so
// its 4MB L2 retains its weight slice instead of streaming all of W from L3.
// Bijective for NBX,NBY powers of two; pure renumbering (correctness-neutral).
template<int NBXPX, int NBY>
__device__ __forceinline__ void xcd_decode(int& bx, int& by) {
    int id  = blockIdx.x;
    int xcd = id & 7, i = id >> 3;
    bx = xcd * NBXPX + (i & (NBXPX - 1));
    by = i / NBXPX;
}

// 1 = bf16 inputs; detector kept as insurance.
__global__ void detect_k(const u32* __restrict__ st, int* __restrict__ flag) {
    u32 w = st[threadIdx.x];
    int e = (w >> 7) & 0xFF;
    unsigned long long m = __ballot(e >= 100 && e <= 140);
    if (threadIdx.x == 0) flag[0] = (__popcll(m) >= 32) ? 1 : 0;
}

// hs0 build + rewards zero + (big ws) fc1s = fc1_W[:,:S] + fc1_W[:,S:]
__global__ __launch_bounds__(256)
void prep_k(const void* __restrict__ state, const void* __restrict__ act,
            const void* __restrict__ latent, const void* __restrict__ fc1W,
            u16* __restrict__ hs, u16* __restrict__ fc1s, float* __restrict__ rewbuf,
            const int* __restrict__ flagp, int big)
{
    const bool bfe = (flagp[0] == 1);
    int g0 = blockIdx.x * 256 + threadIdx.x;
    int stride = gridDim.x * 256;
    for (int i = g0; i < Bb * SAPd; i += stride) {
        int b = i / SAPd, k = i - b * SAPd;
        const void* p; size_t src;
        if (k < Ss)           { p = state;  src = (size_t)b * Ss + k; }
        else if (k < Ss + Aa) { p = act;    src = (size_t)b * (Tt * Aa) + (k - Ss); }
        else                  { p = latent; src = (size_t)b * Pp + (k - Ss - Aa); }
        hs[i] = bfe ? ((const u16*)p)[src] : f2bf(((const float*)p)[src]);
    }
    for (int i = g0; i < Tt * Bb; i += stride) rewbuf[i] = 0.0f;
    if (big) {
        for (int i = g0; i < Ss * Ss; i += stride) {
            int n = i >> 11, k = i & 2047;
            float s;
            if (bfe) s = bf2f(((const u16*)fc1W)[(size_t)n * 4096 + k])
                       + bf2f(((const u16*)fc1W)[(size_t)n * 4096 + 2048 + k]);
            else     s = ((const float*)fc1W)[(size_t)n * 4096 + k]
                       + ((const float*)fc1W)[(size_t)n * 4096 + 2048 + k];
            fc1s[i] = f2bf(s);
        }
    }
}

// C[256 x 2048] = relu(A @ W^T (+bias)).  Tile 32(M) x 64(N), 4 waves, wave w
// owns cols c0+w*16..+15.  K-step 64.  Main path: global_load_lds x3/thread
// into 3 LDS buffers, depth-2 prefetch with counted vmcnt(3) + raw s_barrier
// (never drain to 0 in-loop).  LDS XOR-swizzle (16B chunk ^= row&7) applied on
// BOTH sides: pre-swizzled GLOBAL source (gload_lds writes linearly) + same XOR
// on ds_read -> worst 2-way bank aliasing (free).
// Grid: 1-D, 256 blocks; xcd_decode<4,8> -> XCD-local weight slice ~1.1MB.
template<int K, bool BIAS, bool WC, bool FOLD, bool ACT, bool WBF>
__global__ __launch_bounds__(256)
void gemm_k(const u16* __restrict__ Ap, const void* __restrict__ Wp,
            const void* __restrict__ biasp, u16* __restrict__ outp,
            float* __restrict__ cellp,
            u16* __restrict__ hsp, const void* __restrict__ actp, int t,
            const int* __restrict__ flagp)
{
    constexpr int NK = K / 64;
    __shared__ __align__(16) char smem[36864];          // 3 x (4KB A + 8KB B)
    const bool bfe = (flagp[0] == 1);
    const int tid = threadIdx.x;
    const int lane = tid & 63, w = tid >> 6, m16 = lane & 15, q = lane >> 4;
    int bx, by; xcd_decode<4, 8>(bx, by);
    const int r0 = by * 32, c0 = bx * 64;

    if (ACT) {          // refresh act_t slice of hs before the fc GEMM reads it
        if (by == 0) {
            int i = bx * 512 + tid * 2;                 // 32 bx-values x 512 = 16384
            int b = i >> 6, a2 = i & 63;
            if (bfe) {
                u32 v = *(const u32*)((const u16*)actp + ((size_t)b * Tt + t) * Aa + a2);
                *(u32*)(hsp + (size_t)b * SAPd + Ss + a2) = v;
            } else {
                const float* s = (const float*)actp + ((size_t)b * Tt + t) * Aa + a2;
                *(u32*)(hsp + (size_t)b * SAPd + Ss + a2) =
                    (u32)f2bf(s[0]) | ((u32)f2bf(s[1]) << 16);
            }
            VMW0();                                     // retire before counted pipeline
        }
    }

    const int srow = tid >> 3, sch = tid & 7;           // A-tile: 32 rows x 8 chunks
    const int fr2 = 32 + srow;                          // B-tile rows 32..63
    f32x4 acc0 = {}, acc1 = {};
    const bool mainp = (WBF || bfe) && !FOLD;

    auto COMPUTE = [&](int p) {
        const char* bufA = smem + p * 12288;
        const char* bufB = bufA + 4096;
        const int sw = (m16 & 7) << 4;
        #pragma unroll
        for (int kh = 0; kh < 2; kh++) {
            int cb = ((kh << 6) | (q << 4)) ^ sw;
            s8v b  = *(const s8v*)(bufB + (w * 16 + m16) * 128 + cb);
            s8v a0 = *(const s8v*)(bufA + m16 * 128 + cb);
            s8v a1 = *(const s8v*)(bufA + (16 + m16) * 128 + cb);
            acc0 = __builtin_amdgcn_mfma_f32_16x16x32_bf16(a0, b, acc0, 0, 0, 0);
            acc1 = __builtin_amdgcn_mfma_f32_16x16x32_bf16(a1, b, acc1, 0, 0, 0);
        }
    };

    if (mainp) {
        const u16* W16 = (const u16*)Wp;
        auto STAGE = [&](int kt, int p) {
            char* bufA = smem + p * 12288;
            char* bufB = bufA + 4096;
            int kb = kt * 64;
            gl16(Ap + (size_t)(r0 + srow) * K + kb + ((sch ^ (srow & 7)) * 8),
                 bufA + w * 1024);
            gl16(W16 + (size_t)(c0 + srow) * K + kb + ((sch ^ (srow & 7)) * 8),
                 bufB + w * 1024);
            gl16(W16 + (size_t)(c0 + fr2) * K + kb + ((sch ^ (fr2 & 7)) * 8),
                 bufB + 4096 + w * 1024);
        };
        STAGE(0, 0); STAGE(1, 1);
        for (int k = 0; k < NK - 2; k++) {
            VMW3();                                     // tile k landed (k+1 in flight)
            __builtin_amdgcn_s_barrier();               // k visible to all; k-1 free
            STAGE(k + 2, (k + 2) % 3);
            COMPUTE(k % 3);
        }
        VMW3();
        __builtin_amdgcn_s_barrier();
        COMPUTE((NK - 2) % 3);
        VMW0();
        __builtin_amdgcn_s_barrier();
        COMPUTE((NK - 1) % 3);
    } else {
        // fallback: reg-staged double-buffer (FOLD and/or f32 weights)
        u8v fa; u8v rbh[4]; float4 rff[8];
        auto ISSUE = [&](int kt) {
            int kb = kt * 64;
            fa = *(const u8v*)(Ap + (size_t)(r0 + srow) * K + kb + sch * 8);
            if (FOLD) {
                if (bfe) {
                    const u16* p1 = (const u16*)Wp + (size_t)(c0 + srow) * (2 * K) + kb + sch * 8;
                    rbh[0] = *(const u8v*)p1; rbh[1] = *(const u8v*)(p1 + K);
                    const u16* p2 = (const u16*)Wp + (size_t)(c0 + fr2) * (2 * K) + kb + sch * 8;
                    rbh[2] = *(const u8v*)p2; rbh[3] = *(const u8v*)(p2 + K);
                } else {
                    const float* p1 = (const float*)Wp + (size_t)(c0 + srow) * (2 * K) + kb + sch * 8;
                    rff[0] = *(const float4*)p1;       rff[1] = *(const float4*)(p1 + 4);
                    rff[2] = *(const float4*)(p1 + K); rff[3] = *(const float4*)(p1 + K + 4);
                    const float* p2 = (const float*)Wp + (size_t)(c0 + fr2) * (2 * K) + kb + sch * 8;
                    rff[4] = *(const float4*)p2;       rff[5] = *(const float4*)(p2 + 4);
                    rff[6] = *(const float4*)(p2 + K); rff[7] = *(const float4*)(p2 + K + 4);
                }
            } else {
                const float* p1 = (const float*)Wp + (size_t)(c0 + srow) * K + kb + sch * 8;
                rff[0] = *(const float4*)p1; rff[1] = *(const float4*)(p1 + 4);
                const float* p2 = (const float*)Wp + (size_t)(c0 + fr2) * K + kb + sch * 8;
                rff[2] = *(const float4*)p2; rff[3] = *(const float4*)(p2 + 4);
            }
        };
        auto COMMIT = [&](int p) {
            char* bufA = smem + p * 12288;
            char* bufB = bufA + 4096;
            *(u8v*)(bufA + srow * 128 + ((sch ^ (srow & 7)) * 16)) = fa;
            u8v v1, v2;
            if (FOLD) {
                if (bfe) {
                    #pragma unroll
                    for (int j = 0; j < 8; j++) {
                        v1[j] = f2bf(bf2f(rbh[0][j]) + bf2f(rbh[1][j]));
                        v2[j] = f2bf(bf2f(rbh[2][j]) + bf2f(rbh[3][j]));
                    }
                } else {
                    float a0[8], a1[8], b0[8], b1[8];
                    *(float4*)&a0[0] = rff[0]; *(float4*)&a0[4] = rff[1];
                    *(float4*)&a1[0] = rff[2]; *(float4*)&a1[4] = rff[3];
                    *(float4*)&b0[0] = rff[4]; *(float4*)&b0[4] = rff[5];
                    *(float4*)&b1[0] = rff[6]; *(float4*)&b1[4] = rff[7];
                    #pragma unroll
                    for (int j = 0; j < 8; j++) {
                        v1[j] = f2bf(a0[j] + a1[j]);
                        v2[j] = f2bf(b0[j] + b1[j]);
                    }
                }
            } else {
                float a0[8], a1[8];
                *(float4*)&a0[0] = rff[0]; *(float4*)&a0[4] = rff[1];
                *(float4*)&a1[0] = rff[2]; *(float4*)&a1[4] = rff[3];
                #pragma unroll
                for (int j = 0; j < 8; j++) { v1[j] = f2bf(a0[j]); v2[j] = f2bf(a1[j]); }
            }
            *(u8v*)(bufB + srow * 128 + ((sch ^ (srow & 7)) * 16)) = v1;
            *(u8v*)(bufB + fr2 * 128 + ((sch ^ (fr2 & 7)) * 16)) = v2;
        };
        ISSUE(0);
        for (int k = 0; k < NK; k++) {
            __syncthreads();
            COMMIT(k & 1);
            __syncthreads();
            if (k + 1 < NK) ISSUE(k + 1);
            COMPUTE(k & 1);
        }
    }

    const int col = c0 + w * 16 + m16;
    float bv = 0.0f;
    if (BIAS) bv = bfe ? bf2f(((const u16*)biasp)[col]) : ((const float*)biasp)[col];
    #pragma unroll
    for (int r = 0; r < 4; r++) {
        int row0 = r0 + q * 4 + r;
        float v0 = fmaxf(acc0[r] + bv, 0.0f);
        outp[(size_t)row0 * 2048 + col] = f2bf(v0);
        if (WC) cellp[(size_t)row0 * 2048 + col] = v0;
        int row1 = r0 + 16 + q * 4 + r;
        float v1 = fmaxf(acc1[r] + bv, 0.0f);
        outp[(size_t)row1 * 2048 + col] = f2bf(v1);
        if (WC) cellp[(size_t)row1 * 2048 + col] = v1;
    }
}

// Fused: cc = relu(x2 @ W_W^T) + LSTM gates + cell + h' (hs & preds) + reward partial.
// Same pipeline as gemm_k; tile 32 rows x (16 j x 4 gates); wave g owns gate g.
// B-tile row r (0..63) <-> W_W row (r>>4)*2048 + j0 + (r&15).
// Grid: 1-D, 1024 blocks; xcd_decode<16,8> -> XCD-local W_W slice 4MB (~L2).
__global__ __launch_bounds__(256)
void wgates_k(const u16* __restrict__ Ap, const void* __restrict__ Wp,
              float* __restrict__ cbuf, u16* __restrict__ hsp,
              void* __restrict__ dout, const void* __restrict__ rwWp,
              float* __restrict__ rewbuf, int t, const int* __restrict__ flagp)
{
    constexpr int K = 2048, NK = 32;
    __shared__ __align__(16) char smem[36864];
    const bool bfe = (flagp[0] == 1);
    const int tid = threadIdx.x;
    const int lane = tid & 63, g = tid >> 6, m16 = lane & 15, q = lane >> 4;
    int bx, by; xcd_decode<16, 8>(bx, by);
    const int r0 = by * 32, j0 = bx * 16;

    const int srow = tid >> 3, sch = tid & 7;
    const int fr2 = 32 + srow;
    const int wr1 = (srow >> 4) * 2048 + j0 + (srow & 15);   // global W_W rows
    const int wr2 = (fr2 >> 4) * 2048 + j0 + (fr2 & 15);
    f32x4 acc0 = {}, acc1 = {};

    auto COMPUTE = [&](int p) {
        const char* bufA = smem + p * 12288;
        const char* bufB = bufA + 4096;
        const int sw = (m16 & 7) << 4;
        #pragma unroll
        for (int kh = 0; kh < 2; kh++) {
            int cb = ((kh << 6) | (q << 4)) ^ sw;
            s8v b  = *(const s8v*)(bufB + (g * 16 + m16) * 128 + cb);
            s8v a0 = *(const s8v*)(bufA + m16 * 128 + cb);
            s8v a1 = *(const s8v*)(bufA + (16 + m16) * 128 + cb);
            acc0 = __builtin_amdgcn_mfma_f32_16x16x32_bf16(a0, b, acc0, 0, 0, 0);
            acc1 = __builtin_amdgcn_mfma_f32_16x16x32_bf16(a1, b, acc1, 0, 0, 0);
        }
    };

    if (bfe) {
        const u16* W16 = (const u16*)Wp;
        auto STAGE = [&](int kt, int p) {
            char* bufA = smem + p * 12288;
            char* bufB = bufA + 4096;
            int kb = kt * 64;
            gl16(Ap + (size_t)(r0 + srow) * K + kb + ((sch ^ (srow & 7)) * 8),
                 bufA + g * 1024);
            gl16(W16 + (size_t)wr1 * K + kb + ((sch ^ (srow & 7)) * 8),
                 bufB + g * 1024);
            gl16(W16 + (size_t)wr2 * K + kb + ((sch ^ (fr2 & 7)) * 8),
                 bufB + 4096 + g * 1024);
        };
        STAGE(0, 0); STAGE(1, 1);
        for (int k = 0; k < NK - 2; k++) {
            VMW3();
            __builtin_amdgcn_s_barrier();
            STAGE(k + 2, (k + 2) % 3);
            COMPUTE(k % 3);
        }
        VMW3();
        __builtin_amdgcn_s_barrier();
        COMPUTE((NK - 2) % 3);
        VMW0();
        __builtin_amdgcn_s_barrier();
        COMPUTE((NK - 1) % 3);
    } else {
        u8v fa; float4 rff[4];
        auto ISSUE = [&](int kt) {
            int kb = kt * 64;
            fa = *(const u8v*)(Ap + (size_t)(r0 + srow) * K + kb + sch * 8);
            const float* p1 = (const float*)Wp + (size_t)wr1 * K + kb + sch * 8;
            rff[0] = *(const float4*)p1; rff[1] = *(const float4*)(p1 + 4);
            const float* p2 = (const float*)Wp + (size_t)wr2 * K + kb + sch * 8;
            rff[2] = *(const float4*)p2; rff[3] = *(const float4*)(p2 + 4);
        };
        auto COMMIT = [&](int p) {
            char* bufA = smem + p * 12288;
            char* bufB = bufA + 4096;
            *(u8v*)(bufA + srow * 128 + ((sch ^ (srow & 7)) * 16)) = fa;
            float a0[8], a1[8];
            *(float4*)&a0[0] = rff[0]; *(float4*)&a0[4] = rff[1];
            *(float4*)&a1[0] = rff[2]; *(float4*)&a1[4] = rff[3];
            u8v v1, v2;
            #pragma unroll
            for (int j = 0; j < 8; j++) { v1[j] = f2bf(a0[j]); v2[j] = f2bf(a1[j]); }
            *(u8v*)(bufB + srow * 128 + ((sch ^ (srow & 7)) * 16)) = v1;
            *(u8v*)(bufB + fr2 * 128 + ((sch ^ (fr2 & 7)) * 16)) = v2;
        };
        ISSUE(0);
        for (int k = 0; k < NK; k++) {
            __syncthreads();
            COMMIT(k & 1);
            __syncthreads();
            if (k + 1 < NK) ISSUE(k + 1);
            COMPUTE(k & 1);
        }
    }

    __syncthreads();                     // all waves done with LDS tiles
    float* gbuf = (float*)smem;          // overlay: [32 rows][16 j][4 gates] fp32 (8KB)
    #pragma unroll
    for (int r = 0; r < 4; r++) {
        int row0 = q * 4 + r;
        gbuf[(row0 * 16 + m16) * 4 + g] = fmaxf(acc0[r], 0.0f);
        int row1 = 16 + q * 4 + r;
        gbuf[(row1 * 16 + m16) * 4 + g] = fmaxf(acc1[r], 0.0f);
    }
    __syncthreads();

    const int row = tid >> 3, jj = (tid & 7) * 2;
    const int grow = r0 + row, jcol = j0 + jj;
    float2 cold = *(const float2*)&cbuf[(size_t)grow * 2048 + jcol];
    float rw0 = bfe ? bf2f(((const u16*)rwWp)[jcol])     : ((const float*)rwWp)[jcol];
    float rw1 = bfe ? bf2f(((const u16*)rwWp)[jcol + 1]) : ((const float*)rwWp)[jcol + 1];

    float cn[2], hnf[2];
    float coldv[2] = { cold.x, cold.y };
    float rsum = 0.0f;
    #pragma unroll
    for (int u = 0; u < 2; u++) {
        const float* gq = &gbuf[((row * 16) + jj + u) * 4];
        float ig = sigf(gq[0]), fg = sigf(gq[1]), og = sigf(gq[2]), tg = tanhf_(gq[3]);
        float c_ = fg * coldv[u] + ig * tg;
        float hn = og * tanhf_(c_);
        cn[u] = c_; hnf[u] = hn;
        rsum += hn * (u ? rw1 : rw0);
    }
    *(float2*)&cbuf[(size_t)grow * 2048 + jcol] = *(float2*)cn;
    u32 hpack = (u32)f2bf(hnf[0]) | ((u32)f2bf(hnf[1]) << 16);
    *(u32*)&hsp[(size_t)grow * SAPd + jcol] = hpack;
    size_t pb = ((size_t)t * 256 + grow) * 2048 + jcol;
    if (bfe) *(u32*)&((u16*)dout)[pb] = hpack;
    else     { ((float*)dout)[pb] = hnf[0]; ((float*)dout)[pb + 1] = hnf[1]; }

    rsum += __shfl_xor(rsum, 1);
    rsum += __shfl_xor(rsum, 2);
    rsum += __shfl_xor(rsum, 4);
    if ((tid & 7) == 0) atomicAdd(&rewbuf[t * 256 + grow], rsum);
}

__global__ void rewfin_k(const float* __restrict__ rewbuf, void* __restrict__ dout,
                         const void* __restrict__ rwb, const int* __restrict__ flagp) {
    const bool bfe = (flagp[0] == 1);
    int i = blockIdx.x * 256 + threadIdx.x;        // grid 32 -> 8192
    float rb = bfe ? bf2f(((const u16*)rwb)[0]) : ((const float*)rwb)[0];
    float v = rewbuf[i] + rb;
    size_t o = (size_t)Tt * Bb * Ss + i;           // 16777216
    if (bfe) ((u16*)dout)[o] = f2bf(v);
    else     ((float*)dout)[o] = v;
}

extern "C" void kernel_launch(void* const* d_in, const int* in_sizes, int n_in,
                              void* d_out, int out_size, void* d_ws, size_t ws_size,
                              hipStream_t stream)
{
    const void* state  = d_in[0];
    const void* act    = d_in[1];
    const void* latent = d_in[2];
    const void* fcW    = d_in[3];
    const void* fcb    = d_in[4];
    const void* fc1W   = d_in[5];
    const void* fc2W   = d_in[6];
    const void* WW     = d_in[7];
    const void* rwW    = d_in[8];
    const void* rwb    = d_in[9];
    char* ws = (char*)d_ws;

    // ws layout: small path 6.43 MB; big path (+fc1s) 14.81 MB (gated on ws_size)
    int*   flag   = (int*)  (ws + 0);
    u16*   hs     = (u16*)  (ws + 1024);
    u16*   h      = (u16*)  (ws + 1147904);
    u16*   x1     = (u16*)  (ws + 2196480);
    u16*   x2     = (u16*)  (ws + 3245056);
    float* cbuf   = (float*)(ws + 4293632);
    float* rewbuf = (float*)(ws + 6390784);
    u16*   fc1s   = (u16*)  (ws + 6423552);
    const bool big = ws_size >= 14812160ull;       // launch-invariant -> graph-safe

    detect_k<<<dim3(1), dim3(64), 0, stream>>>((const u32*)state, flag);
    prep_k<<<dim3(4096), dim3(256), 0, stream>>>(state, act, latent, fc1W,
                                                 hs, fc1s, rewbuf, flag, big ? 1 : 0);

    // hidden = cell = relu(fc(hs0))
    gemm_k<2240, true, true, false, false, false><<<dim3(256), dim3(256), 0, stream>>>(
        hs, fcW, fcb, h, cbuf, nullptr, nullptr, 0, flag);

    for (int t = 0; t < 32; t++) {
        // x1 = relu(h @ fc1sum^T); by==0 blocks also copy act_t into hs
        if (big)
            gemm_k<2048, false, false, false, true, true><<<dim3(256), dim3(256), 0, stream>>>(
                h, fc1s, nullptr, x1, nullptr, hs, act, t, flag);
        else
            gemm_k<2048, false, false, true, true, false><<<dim3(256), dim3(256), 0, stream>>>(
                h, fc1W, nullptr, x1, nullptr, hs, act, t, flag);
        // x2 = relu(x1 @ fc2^T)
        gemm_k<2048, false, false, false, false, false><<<dim3(256), dim3(256), 0, stream>>>(
            x1, fc2W, nullptr, x2, nullptr, nullptr, nullptr, 0, flag);
        // cc = relu(x2 @ W_W^T) fused with gates/cell/h'/preds/reward-partial
        wgates_k<<<dim3(1024), dim3(256), 0, stream>>>(
            x2, WW, cbuf, hs, d_out, rwW, rewbuf, t, flag);
        // h = relu(hs @ fc_W^T + b)   (carry discarded at t=31)
        if (t < 31)
            gemm_k<2240, true, false, false, false, false><<<dim3(256), dim3(256), 0, stream>>>(
                hs, fcW, fcb, h, nullptr, nullptr, nullptr, 0, flag);
    }
    rewfin_k<<<dim3(32), dim3(256), 0, stream>>>(rewbuf, d_out, rwb, flag);
}

// Round 6
// 2708.446 us; speedup vs baseline: 1.7869x; 1.1213x over previous
//
#include <hip/hip_runtime.h>

typedef unsigned short u16;
typedef unsigned int   u32;
typedef __attribute__((ext_vector_type(8))) short s8v;            // MFMA bf16 frag
typedef __attribute__((ext_vector_type(8))) unsigned short u8v;
typedef __attribute__((ext_vector_type(4))) unsigned short u4h;
typedef __attribute__((ext_vector_type(4))) float f32x4;

__device__ __forceinline__ float bf2f(u16 v) {
    union { u32 u; float f; } x; x.u = ((u32)v) << 16; return x.f;
}
__device__ __forceinline__ u16 f2bf(float f) {
    union { float f; u32 u; } x; x.f = f;
    return (u16)((x.u + 0x7fffu + ((x.u >> 16) & 1u)) >> 16);
}
__device__ __forceinline__ float sigf(float x)  { return 1.0f / (1.0f + __expf(-x)); }
__device__ __forceinline__ float tanhf_(float x){ return 1.0f - 2.0f / (__expf(2.0f * x) + 1.0f); }

constexpr int Bb = 256, Tt = 32, Ss = 2048, Aa = 64, Pp = 128, SAPd = 2240;

typedef const __attribute__((address_space(1))) unsigned int* gp1_t;
typedef __attribute__((address_space(3))) unsigned int* lp3_t;
__device__ __forceinline__ void gl16(const void* g, void* l) {
    __builtin_amdgcn_global_load_lds((gp1_t)g, (lp3_t)l, 16, 0, 0);
}
#define VMWAIT(n) asm volatile("s_waitcnt vmcnt(" #n ")" ::: "memory")

// XCD-aware decode: hardware round-robins linear block id across the 8 XCDs,
// so xcd = id&7.  Give each XCD a contiguous slice of the N dimension (bx).
// Bijective for power-of-two params; pure renumbering (correctness-neutral).
template<int NBXPX, int NBY>
__device__ __forceinline__ void xcd_decode(int& bx, int& by) {
    int id  = blockIdx.x;
    int xcd = id & 7, i = id >> 3;
    bx = xcd * NBXPX + (i & (NBXPX - 1));
    by = i / NBXPX;
}

// 1 = bf16 inputs; detector kept as insurance.
__global__ void detect_k(const u32* __restrict__ st, int* __restrict__ flag) {
    u32 w = st[threadIdx.x];
    int e = (w >> 7) & 0xFF;
    unsigned long long m = __ballot(e >= 100 && e <= 140);
    if (threadIdx.x == 0) flag[0] = (__popcll(m) >= 32) ? 1 : 0;
}

// hs0 build + rewards zero + (big ws) fc1s = fc1_W[:,:S] + fc1_W[:,S:]
__global__ __launch_bounds__(256)
void prep_k(const void* __restrict__ state, const void* __restrict__ act,
            const void* __restrict__ latent, const void* __restrict__ fc1W,
            u16* __restrict__ hs, u16* __restrict__ fc1s, float* __restrict__ rewbuf,
            const int* __restrict__ flagp, int big)
{
    const bool bfe = (flagp[0] == 1);
    int g0 = blockIdx.x * 256 + threadIdx.x;
    int stride = gridDim.x * 256;
    for (int i = g0; i < Bb * SAPd; i += stride) {
        int b = i / SAPd, k = i - b * SAPd;
        const void* p; size_t src;
        if (k < Ss)           { p = state;  src = (size_t)b * Ss + k; }
        else if (k < Ss + Aa) { p = act;    src = (size_t)b * (Tt * Aa) + (k - Ss); }
        else                  { p = latent; src = (size_t)b * Pp + (k - Ss - Aa); }
        hs[i] = bfe ? ((const u16*)p)[src] : f2bf(((const float*)p)[src]);
    }
    for (int i = g0; i < Tt * Bb; i += stride) rewbuf[i] = 0.0f;
    if (big) {
        for (int i = g0; i < Ss * Ss; i += stride) {
            int n = i >> 11, k = i & 2047;
            float s;
            if (bfe) s = bf2f(((const u16*)fc1W)[(size_t)n * 4096 + k])
                       + bf2f(((const u16*)fc1W)[(size_t)n * 4096 + 2048 + k]);
            else     s = ((const float*)fc1W)[(size_t)n * 4096 + k]
                       + ((const float*)fc1W)[(size_t)n * 4096 + 2048 + k];
            fc1s[i] = f2bf(s);
        }
    }
}

// C[256 x 2048] = relu(A @ W^T (+bias)).  Tile 32(M) x 64(N), 4 waves =
// 2 col-halves (ct: cols ct*32..+31, 2 col-frags) x 2 K-halves (khw).
// Per wave-iter: 4 ds_read_b128 -> 4 MFMA (was 6 reads -> 4): block LDS reads
// 24->16 per iter.  Staging/pipeline identical to R5 (3 gl16/thread, 3 bufs,
// depth-2 prefetch, counted vmcnt(3), XOR swizzle both-sides).  Epilogue:
// K-half reduction via 8KB LDS past the 3 buffers, khw=0 waves store.
template<int K, bool BIAS, bool WC, bool FOLD, bool ACT, bool WBF>
__global__ __launch_bounds__(256)
void gemm_k(const u16* __restrict__ Ap, const void* __restrict__ Wp,
            const void* __restrict__ biasp, u16* __restrict__ outp,
            float* __restrict__ cellp,
            u16* __restrict__ hsp, const void* __restrict__ actp, int t,
            const int* __restrict__ flagp)
{
    constexpr int NK = K / 64;
    __shared__ __align__(16) char smem[36864 + 8192];   // 3 x (4KB A + 8KB B) + red
    const bool bfe = (flagp[0] == 1);
    const int tid = threadIdx.x;
    const int lane = tid & 63, w = tid >> 6, m16 = lane & 15, q = lane >> 4;
    const int ct = w & 1, khw = w >> 1;
    int bx, by; xcd_decode<4, 8>(bx, by);
    const int r0 = by * 32, c0 = bx * 64;

    if (ACT) {          // refresh act_t slice of hs before the fc GEMM reads it
        if (by == 0) {
            int i = bx * 512 + tid * 2;                 // 32 bx-values x 512 = 16384
            int b = i >> 6, a2 = i & 63;
            if (bfe) {
                u32 v = *(const u32*)((const u16*)actp + ((size_t)b * Tt + t) * Aa + a2);
                *(u32*)(hsp + (size_t)b * SAPd + Ss + a2) = v;
            } else {
                const float* s = (const float*)actp + ((size_t)b * Tt + t) * Aa + a2;
                *(u32*)(hsp + (size_t)b * SAPd + Ss + a2) =
                    (u32)f2bf(s[0]) | ((u32)f2bf(s[1]) << 16);
            }
            VMWAIT(0);                                  // retire before counted pipeline
        }
    }

    const int srow = tid >> 3, sch = tid & 7;           // A-tile: 32 rows x 8 chunks
    const int fr2 = 32 + srow;                          // B-tile rows 32..63
    f32x4 acc[4] = {};                                  // [cf*2+af]
    const bool mainp = (WBF || bfe) && !FOLD;

    auto COMPUTE = [&](int p) {
        const char* bufA = smem + p * 12288;
        const char* bufB = bufA + 4096;
        const int sw = (m16 & 7) << 4;
        const int cb = ((khw << 6) | (q << 4)) ^ sw;
        s8v a0 = *(const s8v*)(bufA + m16 * 128 + cb);
        s8v a1 = *(const s8v*)(bufA + (16 + m16) * 128 + cb);
        s8v b0 = *(const s8v*)(bufB + (ct * 32 + m16) * 128 + cb);
        s8v b1 = *(const s8v*)(bufB + (ct * 32 + 16 + m16) * 128 + cb);
        acc[0] = __builtin_amdgcn_mfma_f32_16x16x32_bf16(a0, b0, acc[0], 0, 0, 0);
        acc[1] = __builtin_amdgcn_mfma_f32_16x16x32_bf16(a1, b0, acc[1], 0, 0, 0);
        acc[2] = __builtin_amdgcn_mfma_f32_16x16x32_bf16(a0, b1, acc[2], 0, 0, 0);
        acc[3] = __builtin_amdgcn_mfma_f32_16x16x32_bf16(a1, b1, acc[3], 0, 0, 0);
    };

    if (mainp) {
        const u16* W16 = (const u16*)Wp;
        auto STAGE = [&](int kt, int p) {
            char* bufA = smem + p * 12288;
            char* bufB = bufA + 4096;
            int kb = kt * 64;
            gl16(Ap + (size_t)(r0 + srow) * K + kb + ((sch ^ (srow & 7)) * 8),
                 bufA + w * 1024);
            gl16(W16 + (size_t)(c0 + srow) * K + kb + ((sch ^ (srow & 7)) * 8),
                 bufB + w * 1024);
            gl16(W16 + (size_t)(c0 + fr2) * K + kb + ((sch ^ (fr2 & 7)) * 8),
                 bufB + 4096 + w * 1024);
        };
        STAGE(0, 0); STAGE(1, 1);
        for (int k = 0; k < NK - 2; k++) {
            VMWAIT(3);                                  // tile k landed (k+1 in flight)
            __builtin_amdgcn_s_barrier();               // k visible to all; k-1 free
            STAGE(k + 2, (k + 2) % 3);
            COMPUTE(k % 3);
        }
        VMWAIT(3);
        __builtin_amdgcn_s_barrier();
        COMPUTE((NK - 2) % 3);
        VMWAIT(0);
        __builtin_amdgcn_s_barrier();
        COMPUTE((NK - 1) % 3);
    } else {
        // fallback: reg-staged double-buffer (FOLD and/or f32 weights)
        u8v fa; u8v rbh[4]; float4 rff[8];
        auto ISSUE = [&](int kt) {
            int kb = kt * 64;
            fa = *(const u8v*)(Ap + (size_t)(r0 + srow) * K + kb + sch * 8);
            if (FOLD) {
                if (bfe) {
                    const u16* p1 = (const u16*)Wp + (size_t)(c0 + srow) * (2 * K) + kb + sch * 8;
                    rbh[0] = *(const u8v*)p1; rbh[1] = *(const u8v*)(p1 + K);
                    const u16* p2 = (const u16*)Wp + (size_t)(c0 + fr2) * (2 * K) + kb + sch * 8;
                    rbh[2] = *(const u8v*)p2; rbh[3] = *(const u8v*)(p2 + K);
                } else {
                    const float* p1 = (const float*)Wp + (size_t)(c0 + srow) * (2 * K) + kb + sch * 8;
                    rff[0] = *(const float4*)p1;       rff[1] = *(const float4*)(p1 + 4);
                    rff[2] = *(const float4*)(p1 + K); rff[3] = *(const float4*)(p1 + K + 4);
                    const float* p2 = (const float*)Wp + (size_t)(c0 + fr2) * (2 * K) + kb + sch * 8;
                    rff[4] = *(const float4*)p2;       rff[5] = *(const float4*)(p2 + 4);
                    rff[6] = *(const float4*)(p2 + K); rff[7] = *(const float4*)(p2 + K + 4);
                }
            } else {
                const float* p1 = (const float*)Wp + (size_t)(c0 + srow) * K + kb + sch * 8;
                rff[0] = *(const float4*)p1; rff[1] = *(const float4*)(p1 + 4);
                const float* p2 = (const float*)Wp + (size_t)(c0 + fr2) * K + kb + sch * 8;
                rff[2] = *(const float4*)p2; rff[3] = *(const float4*)(p2 + 4);
            }
        };
        auto COMMIT = [&](int p) {
            char* bufA = smem + p * 12288;
            char* bufB = bufA + 4096;
            *(u8v*)(bufA + srow * 128 + ((sch ^ (srow & 7)) * 16)) = fa;
            u8v v1, v2;
            if (FOLD) {
                if (bfe) {
                    #pragma unroll
                    for (int j = 0; j < 8; j++) {
                        v1[j] = f2bf(bf2f(rbh[0][j]) + bf2f(rbh[1][j]));
                        v2[j] = f2bf(bf2f(rbh[2][j]) + bf2f(rbh[3][j]));
                    }
                } else {
                    float a0[8], a1[8], b0[8], b1[8];
                    *(float4*)&a0[0] = rff[0]; *(float4*)&a0[4] = rff[1];
                    *(float4*)&a1[0] = rff[2]; *(float4*)&a1[4] = rff[3];
                    *(float4*)&b0[0] = rff[4]; *(float4*)&b0[4] = rff[5];
                    *(float4*)&b1[0] = rff[6]; *(float4*)&b1[4] = rff[7];
                    #pragma unroll
                    for (int j = 0; j < 8; j++) {
                        v1[j] = f2bf(a0[j] + a1[j]);
                        v2[j] = f2bf(b0[j] + b1[j]);
                    }
                }
            } else {
                float a0[8], a1[8];
                *(float4*)&a0[0] = rff[0]; *(float4*)&a0[4] = rff[1];
                *(float4*)&a1[0] = rff[2]; *(float4*)&a1[4] = rff[3];
                #pragma unroll
                for (int j = 0; j < 8; j++) { v1[j] = f2bf(a0[j]); v2[j] = f2bf(a1[j]); }
            }
            *(u8v*)(bufB + srow * 128 + ((sch ^ (srow & 7)) * 16)) = v1;
            *(u8v*)(bufB + fr2 * 128 + ((sch ^ (fr2 & 7)) * 16)) = v2;
        };
        ISSUE(0);
        for (int k = 0; k < NK; k++) {
            __syncthreads();
            COMMIT(k & 1);
            __syncthreads();
            if (k + 1 < NK) ISSUE(k + 1);
            COMPUTE(k & 1);
        }
    }

    // K-half reduction (red lives past the 3 buffers -> no overlay hazard)
    f32x4* red = (f32x4*)(smem + 36864);
    if (khw == 1) {
        #pragma unroll
        for (int f = 0; f < 4; f++) red[(ct * 4 + f) * 64 + lane] = acc[f];
    }
    __syncthreads();
    if (khw == 0) {
        #pragma unroll
        for (int f = 0; f < 4; f++) acc[f] += red[(ct * 4 + f) * 64 + lane];
        #pragma unroll
        for (int cf = 0; cf < 2; cf++) {
            const int col = c0 + ct * 32 + cf * 16 + m16;
            float bv = 0.0f;
            if (BIAS) bv = bfe ? bf2f(((const u16*)biasp)[col]) : ((const float*)biasp)[col];
            #pragma unroll
            for (int af = 0; af < 2; af++) {
                f32x4 a = acc[cf * 2 + af];
                #pragma unroll
                for (int r = 0; r < 4; r++) {
                    int row = r0 + af * 16 + q * 4 + r;
                    float v = fmaxf(a[r] + bv, 0.0f);
                    outp[(size_t)row * 2048 + col] = f2bf(v);
                    if (WC) cellp[(size_t)row * 2048 + col] = v;
                }
            }
        }
    }
}

// Fused: cc = relu(x2 @ W_W^T) + LSTM gates + cell + h' (hs & preds) + reward partial.
// Tile 64(M rows) x 64(16 j x 4 gates), 4 waves = 2 row-halves (mi) x 2 K-halves
// (khw); per wave-iter 6 ds_read -> 8 MFMA (2x better MFMA/LDS-read than R5).
// Grid 512 (bx: j-slice 0..127, by: row-slice 0..3), XCD-sliced.
// B-tile row b <-> W_W row (b>>4)*2048 + j0 + (b&15).
// Epilogue: K-half reduction + gate buffer both overlay buf2 (free after the
// pre-final barrier; final tile is in buf1); per-(mi) regions are disjoint.
__global__ __launch_bounds__(256)
void wgates_k(const u16* __restrict__ Ap, const void* __restrict__ Wp,
              float* __restrict__ cbuf, u16* __restrict__ hsp,
              void* __restrict__ dout, const void* __restrict__ rwWp,
              float* __restrict__ rewbuf, int t, const int* __restrict__ flagp)
{
    constexpr int K = 2048, NK = 32;
    __shared__ __align__(16) char smem[49152];          // 3 x (8KB A + 8KB B)
    const bool bfe = (flagp[0] == 1);
    const int tid = threadIdx.x;
    const int lane = tid & 63, w = tid >> 6, m16 = lane & 15, q = lane >> 4;
    const int mi = w & 1, khw = w >> 1;
    int bx, by; xcd_decode<16, 4>(bx, by);
    const int r0 = by * 64, j0 = bx * 16;

    const int srow8 = lane >> 3, sch = lane & 7;        // within-segment row/chunk
    f32x4 acc[8] = {};                                  // [cf*2+af]

    auto COMPUTE = [&](int p) {
        const char* bufA = smem + p * 16384;
        const char* bufB = bufA + 8192;
        const int sw = (m16 & 7) << 4;
        const int cb = ((khw << 6) | (q << 4)) ^ sw;
        s8v a0 = *(const s8v*)(bufA + (mi * 32 + m16) * 128 + cb);
        s8v a1 = *(const s8v*)(bufA + (mi * 32 + 16 + m16) * 128 + cb);
        #pragma unroll
        for (int cf = 0; cf < 4; cf++) {
            s8v b = *(const s8v*)(bufB + (cf * 16 + m16) * 128 + cb);
            acc[cf * 2 + 0] = __builtin_amdgcn_mfma_f32_16x16x32_bf16(a0, b, acc[cf * 2 + 0], 0, 0, 0);
            acc[cf * 2 + 1] = __builtin_amdgcn_mfma_f32_16x16x32_bf16(a1, b, acc[cf * 2 + 1], 0, 0, 0);
        }
    };

    if (bfe) {
        const u16* W16 = (const u16*)Wp;
        auto STAGE = [&](int kt, int p) {
            char* bufA = smem + p * 16384;
            char* bufB = bufA + 8192;
            int kb = kt * 64;
            #pragma unroll
            for (int i = 0; i < 2; i++) {               // A: 8 segs, 2 per wave
                int s = w * 2 + i;
                int row = s * 8 + srow8;
                int cg = sch ^ (row & 7);
                gl16(Ap + (size_t)(r0 + row) * K + kb + cg * 8, bufA + s * 1024);
            }
            #pragma unroll
            for (int i = 0; i < 2; i++) {               // B: 8 segs, 2 per wave
                int s = w * 2 + i;
                int row = s * 8 + srow8;
                int wr = (row >> 4) * 2048 + j0 + (row & 15);
                int cg = sch ^ (row & 7);
                gl16(W16 + (size_t)wr * K + kb + cg * 8, bufB + s * 1024);
            }
        };
        STAGE(0, 0); STAGE(1, 1);
        for (int k = 0; k < NK - 2; k++) {
            VMWAIT(4);                                  // 4 gl16/thread/STAGE
            __builtin_amdgcn_s_barrier();
            STAGE(k + 2, (k + 2) % 3);
            COMPUTE(k % 3);
        }
        VMWAIT(4);
        __builtin_amdgcn_s_barrier();
        COMPUTE((NK - 2) % 3);
        VMWAIT(0);
        __builtin_amdgcn_s_barrier();
        COMPUTE((NK - 1) % 3);
    } else {
        // fallback: A via gl16, B (f32 W_W) reg-staged
        float4 rff[4];
        auto ISSUE = [&](int kt) {
            int kb = kt * 64;
            #pragma unroll
            for (int i = 0; i < 2; i++) {
                int slot = tid + i * 256;
                int brow = slot >> 3, bch = slot & 7;
                int wr = (brow >> 4) * 2048 + j0 + (brow & 15);
                int cg = bch ^ (brow & 7);
                const float* p1 = (const float*)Wp + (size_t)wr * K + kb + cg * 8;
                rff[2 * i] = *(const float4*)p1; rff[2 * i + 1] = *(const float4*)(p1 + 4);
            }
        };
        auto STAGE_A = [&](int kt, int p) {
            char* bufA = smem + p * 16384;
            int kb = kt * 64;
            #pragma unroll
            for (int i = 0; i < 2; i++) {
                int s = w * 2 + i;
                int row = s * 8 + srow8;
                int cg = sch ^ (row & 7);
                gl16(Ap + (size_t)(r0 + row) * K + kb + cg * 8, bufA + s * 1024);
            }
        };
        auto COMMIT = [&](int p) {
            char* bufB = smem + p * 16384 + 8192;
            #pragma unroll
            for (int i = 0; i < 2; i++) {
                int slot = tid + i * 256;
                int brow = slot >> 3, bch = slot & 7;
                float a0[8];
                *(float4*)&a0[0] = rff[2 * i]; *(float4*)&a0[4] = rff[2 * i + 1];
                u8v v;
                #pragma unroll
                for (int j = 0; j < 8; j++) v[j] = f2bf(a0[j]);
                *(u8v*)(bufB + brow * 128 + bch * 16) = v;
            }
        };
        ISSUE(0); STAGE_A(0, 0);
        for (int k = 0; k < NK; k++) {
            __syncthreads();
            COMMIT(k & 1);
            __syncthreads();
            if (k + 1 < NK) { STAGE_A(k + 1, (k + 1) & 1); ISSUE(k + 1); }
            COMPUTE(k & 1);
        }
    }

    // K-half reduction into buf2 region (last tile is buf1; buf2 reads were
    // fenced by the barrier before COMPUTE(NK-1))
    f32x4* red = (f32x4*)(smem + 32768);
    if (khw == 1) {
        #pragma unroll
        for (int f = 0; f < 8; f++) red[(mi * 8 + f) * 64 + lane] = acc[f];
    }
    __syncthreads();
    float* gbuf = (float*)(smem + 32768);   // [64 rows][16 j][4 gates] fp32, reuses red
    if (khw == 0) {
        #pragma unroll
        for (int f = 0; f < 8; f++) acc[f] += red[(mi * 8 + f) * 64 + lane];
        // wave mi reads red rows mi*... and writes gbuf rows mi*32..+31:
        // same 8KB half per mi -> register-ordered, no cross-wave hazard.
        #pragma unroll
        for (int af = 0; af < 2; af++)
            #pragma unroll
            for (int r = 0; r < 4; r++) {
                int row = mi * 32 + af * 16 + q * 4 + r;
                f32x4 gv;
                #pragma unroll
                for (int cf = 0; cf < 4; cf++) gv[cf] = fmaxf(acc[cf * 2 + af][r], 0.0f);
                ((f32x4*)gbuf)[row * 16 + m16] = gv;
            }
    }
    __syncthreads();

    const int row = tid >> 2, jq = (tid & 3) * 4;
    const int grow = r0 + row, jcol = j0 + jq;
    float4 cold = *(const float4*)&cbuf[(size_t)grow * 2048 + jcol];
    float coldv[4] = { cold.x, cold.y, cold.z, cold.w };
    float rw4[4];
    #pragma unroll
    for (int u = 0; u < 4; u++)
        rw4[u] = bfe ? bf2f(((const u16*)rwWp)[jcol + u]) : ((const float*)rwWp)[jcol + u];

    float cn[4], hnf[4]; u4h hv;
    float rsum = 0.0f;
    #pragma unroll
    for (int u = 0; u < 4; u++) {
        const float* gq = &gbuf[((row * 16) + jq + u) * 4];
        float ig = sigf(gq[0]), fg = sigf(gq[1]), og = sigf(gq[2]), tg = tanhf_(gq[3]);
        float c_ = fg * coldv[u] + ig * tg;
        float hn = og * tanhf_(c_);
        cn[u] = c_; hnf[u] = hn; hv[u] = f2bf(hn);
        rsum += hn * rw4[u];
    }
    *(float4*)&cbuf[(size_t)grow * 2048 + jcol] = *(float4*)cn;
    *(u4h*)&hsp[(size_t)grow * SAPd + jcol] = hv;
    size_t pb = ((size_t)t * 256 + grow) * 2048 + jcol;
    if (bfe) *(u4h*)&((u16*)dout)[pb] = hv;
    else {
        #pragma unroll
        for (int u = 0; u < 4; u++) ((float*)dout)[pb + u] = hnf[u];
    }

    rsum += __shfl_xor(rsum, 1);
    rsum += __shfl_xor(rsum, 2);
    if ((tid & 3) == 0) atomicAdd(&rewbuf[t * 256 + grow], rsum);
}

__global__ void rewfin_k(const float* __restrict__ rewbuf, void* __restrict__ dout,
                         const void* __restrict__ rwb, const int* __restrict__ flagp) {
    const bool bfe = (flagp[0] == 1);
    int i = blockIdx.x * 256 + threadIdx.x;        // grid 32 -> 8192
    float rb = bfe ? bf2f(((const u16*)rwb)[0]) : ((const float*)rwb)[0];
    float v = rewbuf[i] + rb;
    size_t o = (size_t)Tt * Bb * Ss + i;           // 16777216
    if (bfe) ((u16*)dout)[o] = f2bf(v);
    else     ((float*)dout)[o] = v;
}

extern "C" void kernel_launch(void* const* d_in, const int* in_sizes, int n_in,
                              void* d_out, int out_size, void* d_ws, size_t ws_size,
                              hipStream_t stream)
{
    const void* state  = d_in[0];
    const void* act    = d_in[1];
    const void* latent = d_in[2];
    const void* fcW    = d_in[3];
    const void* fcb    = d_in[4];
    const void* fc1W   = d_in[5];
    const void* fc2W   = d_in[6];
    const void* WW     = d_in[7];
    const void* rwW    = d_in[8];
    const void* rwb    = d_in[9];
    char* ws = (char*)d_ws;

    // ws layout: small path 6.43 MB; big path (+fc1s) 14.81 MB (gated on ws_size)
    int*   flag   = (int*)  (ws + 0);
    u16*   hs     = (u16*)  (ws + 1024);
    u16*   h      = (u16*)  (ws + 1147904);
    u16*   x1     = (u16*)  (ws + 2196480);
    u16*   x2     = (u16*)  (ws + 3245056);
    float* cbuf   = (float*)(ws + 4293632);
    float* rewbuf = (float*)(ws + 6390784);
    u16*   fc1s   = (u16*)  (ws + 6423552);
    const bool big = ws_size >= 14812160ull;       // launch-invariant -> graph-safe

    detect_k<<<dim3(1), dim3(64), 0, stream>>>((const u32*)state, flag);
    prep_k<<<dim3(4096), dim3(256), 0, stream>>>(state, act, latent, fc1W,
                                                 hs, fc1s, rewbuf, flag, big ? 1 : 0);

    // hidden = cell = relu(fc(hs0))
    gemm_k<2240, true, true, false, false, false><<<dim3(256), dim3(256), 0, stream>>>(
        hs, fcW, fcb, h, cbuf, nullptr, nullptr, 0, flag);

    for (int t = 0; t < 32; t++) {
        // x1 = relu(h @ fc1sum^T); by==0 blocks also copy act_t into hs
        if (big)
            gemm_k<2048, false, false, false, true, true><<<dim3(256), dim3(256), 0, stream>>>(
                h, fc1s, nullptr, x1, nullptr, hs, act, t, flag);
        else
            gemm_k<2048, false, false, true, true, false><<<dim3(256), dim3(256), 0, stream>>>(
                h, fc1W, nullptr, x1, nullptr, hs, act, t, flag);
        // x2 = relu(x1 @ fc2^T)
        gemm_k<2048, false, false, false, false, false><<<dim3(256), dim3(256), 0, stream>>>(
            x1, fc2W, nullptr, x2, nullptr, nullptr, nullptr, 0, flag);
        // cc = relu(x2 @ W_W^T) fused with gates/cell/h'/preds/reward-partial
        wgates_k<<<dim3(512), dim3(256), 0, stream>>>(
            x2, WW, cbuf, hs, d_out, rwW, rewbuf, t, flag);
        // h = relu(hs @ fc_W^T + b)   (carry discarded at t=31)
        if (t < 31)
            gemm_k<2240, true, false, false, false, false><<<dim3(256), dim3(256), 0, stream>>>(
                hs, fcW, fcb, h, nullptr, nullptr, nullptr, 0, flag);
    }
    rewfin_k<<<dim3(32), dim3(256), 0, stream>>>(rewbuf, d_out, rwb, flag);
}